// Round 4
// baseline (1107.086 us; speedup 1.0000x reference)
//
#include <hip/hip_runtime.h>
#include <math.h>

#define BATCH 32
#define NN 1024
#define MM 1024
#define GB 8                    // bands (blocks) per batch
#define BAND (NN / GB)          // 128 rows per band
#define LANES 64
#define CHUNK 32                // boundary handoff granularity (columns)
#define DSTEPS (MM + LANES - 1) // 1087
#define WPR (MM / 8)            // decision words along j per row-pair: 128
#define RPB (NN / 2)            // row-pairs per batch: 512
#define DEC_WORDS_PER_BATCH (WPR * RPB)      // 65536
#define DEC_BYTES ((size_t)BATCH * DEC_WORDS_PER_BATCH * 4)  // 8 MB
#define BND_FLOATS ((size_t)BATCH * GB * MM) // 262144
#define BND_BYTES (BND_FLOATS * 4)           // 1 MB
#define CNT_INTS (BATCH * GB)
#define REQ_WS (DEC_BYTES + BND_BYTES + (size_t)CNT_INTS * 4)
#define LPATH (NN + MM - 1)     // 2047
#define BT_T 256

__global__ void init_kernel(float* out, int* cnt) {
    const int k = threadIdx.x;
    if (k == 0) out[0] = 0.0f;
    if (k < CNT_INTS) cnt[k] = 0;
    if (k + 256 < CNT_INTS) cnt[k + 256] = 0;
}

// ---------------- DP kernel: 256 blocks (batch x band) x 64 threads ----------
// Lane t owns rows i0=128g+2t, i0+1. At step s it processes column j = s - t.
// Intra-block boundary: __shfl_up of previous step's bottom-row D (lockstep).
// Cross-block boundary: block g-1 publishes its bottom row to bnd[] per column
// and bumps an agent-scope release counter every CHUNK columns; block g gates
// on the (cached) counter with an acquire load. Decisions: 2 bits/cell packed
// 8 cols x 2 rows per u32, layout dec[b][j>>3][i>>1] (coalesced-ish stores,
// LDS-stageable for backtrack).
__global__ __launch_bounds__(LANES) void dtw_dp(
    const float* __restrict__ preds, const float* __restrict__ targs,
    unsigned* __restrict__ dec, float* __restrict__ bnd, int* __restrict__ cnt)
{
    const int blk = blockIdx.x;
    const int b = blk >> 3;
    const int g = blk & 7;
    const int t = threadIdx.x;
    const float INF = __builtin_inff();

    __shared__ float txy[2 * MM];
    __shared__ float bndbuf[CHUNK];

    for (int it = 0; it < MM / LANES; ++it) {
        const int idx = it * LANES + t;
        const float4 t4 = ((const float4*)targs)[(size_t)b * MM + idx];
        txy[2 * idx] = t4.x; txy[2 * idx + 1] = t4.y;
    }
    __syncthreads();

    const int i0 = g * BAND + 2 * t;
    const float4 p0 = ((const float4*)preds)[(size_t)b * NN + i0];
    const float4 p1 = ((const float4*)preds)[(size_t)b * NN + i0 + 1];
    const float px0 = p0.x, py0 = p0.y, px1 = p1.x, py1 = p1.y;

    unsigned* __restrict__ decB = dec + (size_t)b * DEC_WORDS_PER_BATCH;
    const int ri = i0 >> 1;                                  // 64g + t
    const float* __restrict__ bndIn = bnd + ((size_t)b * GB + (g - 1)) * MM;
    float* __restrict__ bndOut      = bnd + ((size_t)b * GB + g) * MM;
    const int* cntIn = cnt + b * GB + (g - 1);
    int* cntOut      = cnt + b * GB + g;

    float Dp0 = INF, Dp1 = INF, Dbot = INF;
    float dgB = (g == 0 && t == 0) ? 0.0f : INF;  // (0,0) seed: dg=0 reproduces
                                                  // the reference inf->0 sub exactly
    int avail = 0;
    unsigned packed = 0;
    float txc = txy[0], tyc = txy[1];             // coords for j (prefetched)
    float btc = INF;                              // top-boundary value for lane 0

    for (int s = 0; s < DSTEPS; ++s) {
        const int j = s - t;
        if (g > 0 && s < MM && (s & (CHUNK - 1)) == 0) {       // uniform gate
            const int need = (s >> 5) + 1;
            if (avail < need) {
                do {
                    __builtin_amdgcn_s_sleep(2);
                    avail = __hip_atomic_load(cntIn, __ATOMIC_ACQUIRE,
                                              __HIP_MEMORY_SCOPE_AGENT);
                } while (avail < need);
            }
            if (t < CHUNK) bndbuf[t] = bndIn[s + t];
            btc = bndbuf[s & (CHUNK - 1)];        // fresh read after refill
        }
        float upB = __shfl_up(Dbot, 1);
        if (t == 0) upB = (g > 0 && s < MM) ? btc : INF;

        if (j >= 0 && j < MM) {
            const float dx0 = px0 - txc, dy0 = py0 - tyc;
            const float dx1 = px1 - txc, dy1 = py1 - tyc;
            const float c0 = __builtin_amdgcn_sqrtf(dx0 * dx0 + dy0 * dy0);
            const float c1 = __builtin_amdgcn_sqrtf(dx1 * dx1 + dy1 * dy1);
            const float lf0 = Dp0;
            // JAX argmin over [dg, up, lf], first-minimum tie order.
            const unsigned m0 = (dgB <= upB && dgB <= lf0) ? 0u
                              : ((upB <= lf0) ? 1u : 2u);
            const float D0 = c0 + fminf(upB, fminf(dgB, lf0));
            const float lf1 = Dp1;
            const unsigned m1 = (lf0 <= D0 && lf0 <= lf1) ? 0u
                              : ((D0 <= lf1) ? 1u : 2u);
            const float D1 = c1 + fminf(D0, fminf(lf0, lf1));
            Dp0 = D0; Dp1 = D1; Dbot = D1;
            const int k = j & 7;
            packed |= (m0 << (k * 4)) | (m1 << (k * 4 + 2));
            if (k == 7) { decB[(j >> 3) * RPB + ri] = packed; packed = 0; }
            if (g < GB - 1 && t == LANES - 1) {
                bndOut[j] = D1;
                if ((j & (CHUNK - 1)) == CHUNK - 1)
                    __hip_atomic_store(cntOut, (j >> 5) + 1, __ATOMIC_RELEASE,
                                       __HIP_MEMORY_SCOPE_AGENT);
            }
        }
        dgB = upB;
        // Prefetch next step's uniform boundary + per-lane coords (latency
        // hidden across the iteration; gate steps re-read btc after refill).
        btc = bndbuf[(s + 1) & (CHUNK - 1)];
        int jn = j + 1;
        jn = jn < 0 ? 0 : (jn > MM - 1 ? MM - 1 : jn);
        txc = txy[2 * jn]; tyc = txy[2 * jn + 1];
    }
}

// ---------------- Backtrack kernel: 32 blocks x 256 threads ------------------
// Stage half the batch's decision words (128 KB) into LDS, walk the path as a
// pure LDS pointer-chase with 3-candidate prefetch, emit path to LDS, then
// compute the loss in parallel.
__device__ inline void bt_walk(const unsigned* __restrict__ sdec, int roff,
                               int iLow, int& i, int& j, int& n,
                               unsigned* __restrict__ path)
{
    int ri = i >> 1, jc = j >> 3;
    unsigned w = sdec[jc * 256 + (ri - roff)];
    while (true) {
        const int tjl = (jc > 0) ? jc - 1 : 0;
        const int til = (ri > roff) ? ri - 1 : roff;
        const unsigned wl = sdec[jc  * 256 + (ri - roff)  - (jc > 0 ? 256 : 0)];
        const unsigned wu = sdec[jc  * 256 + (til - roff)];
        const unsigned wd = sdec[tjl * 256 + (til - roff)];
        bool done = false, susp = false;
        while (true) {
            path[n++] = ((unsigned)i << 16) | (unsigned)j;
            if ((i | j) == 0) { done = true; break; }
            const unsigned m = (w >> ((j & 7) * 4 + (i & 1) * 2)) & 3u;
            i -= (m != 2u); j -= (m != 1u);
            if (i < iLow) { susp = true; break; }
            if ((i >> 1) != ri || (j >> 3) != jc) break;
        }
        if (done || susp) break;
        const int nri = i >> 1, njc = j >> 3;
        w = (nri == ri) ? wl : ((njc == jc) ? wu : wd);
        ri = nri; jc = njc;
    }
}

__global__ __launch_bounds__(BT_T) void dtw_bt(
    const float* __restrict__ preds, const float* __restrict__ targs,
    const float* __restrict__ subcoef, const unsigned* __restrict__ dec,
    float* __restrict__ out)
{
    const int b = blockIdx.x, t = threadIdx.x;
    __shared__ float pxA[NN], pyA[NN], txA[MM], tyA[MM];
    __shared__ unsigned sdec[WPR * (RPB / 2)];   // 32768 words = 128 KB
    __shared__ unsigned path[LPATH + 1];
    __shared__ int sI, sJ, sN;
    __shared__ float wsum[BT_T / 64];

    for (int it = 0; it < NN / BT_T; ++it) {
        const int idx = it * BT_T + t;
        const float4 p4 = ((const float4*)preds)[(size_t)b * NN + idx];
        pxA[idx] = p4.x; pyA[idx] = p4.y;
        const float4 t4 = ((const float4*)targs)[(size_t)b * MM + idx];
        txA[idx] = t4.x; tyA[idx] = t4.y;
    }
    const unsigned* __restrict__ decB = dec + (size_t)b * DEC_WORDS_PER_BATCH;

    // Phase A: rows 512..1023 (ri 256..511)
    for (int k = t; k < WPR * 256; k += BT_T)
        sdec[k] = decB[(k >> 8) * RPB + 256 + (k & 255)];
    __syncthreads();
    if (t == 0) {
        int i = NN - 1, j = MM - 1, n = 0;
        bt_walk(sdec, 256, 512, i, j, n, path);
        sI = i; sJ = j; sN = n;
    }
    __syncthreads();
    // Phase B: rows 0..511 (ri 0..255)
    for (int k = t; k < WPR * 256; k += BT_T)
        sdec[k] = decB[(k >> 8) * RPB + (k & 255)];
    __syncthreads();
    if (t == 0) {
        int i = sI, j = sJ, n = sN;
        bt_walk(sdec, 0, 0, i, j, n, path);
        sN = n;
    }
    __syncthreads();

    const float sc0 = subcoef[0], sc1 = subcoef[1];
    const int n = sN;
    float acc = 0.0f;
    for (int p = t; p < n; p += BT_T) {
        const unsigned e = path[p];
        const int i = (int)(e >> 16), j = (int)(e & 0xffffu);
        acc += fabsf(pxA[i] - txA[j]) * sc0 + fabsf(pyA[i] - tyA[j]) * sc1;
    }
    #pragma unroll
    for (int o = 32; o > 0; o >>= 1) acc += __shfl_down(acc, o);
    if ((t & 63) == 0) wsum[t >> 6] = acc;
    __syncthreads();
    if (t == 0) atomicAdd(out, (wsum[0] + wsum[1]) + (wsum[2] + wsum[3]));
}

// ---------------- Fallback (R1 kernel, used only if ws is too small) ---------
__global__ __launch_bounds__(256) void dtw_fallback(
    const float* __restrict__ preds, const float* __restrict__ targs,
    const float* __restrict__ subcoef, unsigned* __restrict__ dec,
    float* __restrict__ out)
{
    const int b = blockIdx.x;
    const int t = threadIdx.x;
    const float INF = __builtin_inff();
    __shared__ float px[NN], py[NN];
    __shared__ float txy[2 * MM];
    __shared__ float bbuf[2][256];

    for (int it = 0; it < NN / 256; ++it) {
        const int idx = it * 256 + t;
        const float4 p4 = ((const float4*)preds)[(size_t)b * NN + idx];
        px[idx] = p4.x; py[idx] = p4.y;
        const float4 t4 = ((const float4*)targs)[(size_t)b * MM + idx];
        txy[2 * idx] = t4.x; txy[2 * idx + 1] = t4.y;
    }
    bbuf[0][t] = INF; bbuf[1][t] = INF;
    __syncthreads();

    float pxr[4], pyr[4], Dp[4];
    #pragma unroll
    for (int r = 0; r < 4; ++r) {
        pxr[r] = px[4 * t + r]; pyr[r] = py[4 * t + r]; Dp[r] = INF;
    }
    float dgB = (t == 0) ? 0.0f : INF;
    unsigned packed = 0;
    unsigned* decB = dec + (size_t)b * 65536;
    for (int s = 0; s < MM + 255; ++s) {
        const int j = s - t;
        const float upB = (t == 0) ? INF : bbuf[(s + 1) & 1][t - 1];
        if (j >= 0 && j < MM) {
            const float txj = txy[2 * j], tyj = txy[2 * j + 1];
            float up = upB, dg = dgB;
            unsigned mbits = 0;
            #pragma unroll
            for (int r = 0; r < 4; ++r) {
                const float dx = pxr[r] - txj, dy = pyr[r] - tyj;
                const float c = sqrtf(dx * dx + dy * dy);
                const float lf = Dp[r];
                const unsigned m = (dg <= up && dg <= lf) ? 0u
                                 : ((up <= lf) ? 1u : 2u);
                mbits |= m << (r * 8 + (j & 3) * 2);
                const float Dc = c + fminf(up, fminf(dg, lf));
                dg = lf; up = Dc; Dp[r] = Dc;
            }
            packed |= mbits;
            if ((j & 3) == 3) { decB[(unsigned)t * 256 + (j >> 2)] = packed; packed = 0; }
            bbuf[s & 1][t] = Dp[3];
        }
        dgB = upB;
        __syncthreads();
    }
    __threadfence_block();
    __syncthreads();
    if (t == 0) {
        const float sc0 = subcoef[0], sc1 = subcoef[1];
        int i = NN - 1, jj = MM - 1;
        float loss = 0.0f;
        int ti = i >> 2, tj = jj >> 2;
        unsigned w = decB[ti * 256 + tj];
        while (true) {
            const int tjl = (tj > 0) ? tj - 1 : 0;
            const int til = (ti > 0) ? ti - 1 : 0;
            const unsigned wl = decB[ti * 256 + tjl];
            const unsigned wu = decB[til * 256 + tj];
            const unsigned wd = decB[til * 256 + tjl];
            bool done = false;
            while (true) {
                loss += fabsf(px[i] - txy[2 * jj]) * sc0
                      + fabsf(py[i] - txy[2 * jj + 1]) * sc1;
                if ((i | jj) == 0) { done = true; break; }
                const unsigned m = (w >> (((i & 3) * 4 + (jj & 3)) * 2)) & 3u;
                i -= (m != 2u); jj -= (m != 1u);
                if ((i >> 2) != ti || (jj >> 2) != tj) break;
            }
            if (done) break;
            const int nti = i >> 2, ntj = jj >> 2;
            w = (nti == ti) ? wl : ((ntj == tj) ? wu : wd);
            ti = nti; tj = ntj;
        }
        atomicAdd(out, loss);
    }
}

extern "C" void kernel_launch(void* const* d_in, const int* in_sizes, int n_in,
                              void* d_out, int out_size, void* d_ws, size_t ws_size,
                              hipStream_t stream) {
    const float* preds   = (const float*)d_in[0];
    const float* targs   = (const float*)d_in[1];
    const float* subcoef = (const float*)d_in[2];
    float* out = (float*)d_out;

    if (ws_size >= REQ_WS) {
        unsigned* dec = (unsigned*)d_ws;
        float* bnd = (float*)((char*)d_ws + DEC_BYTES);
        int* cnt = (int*)((char*)d_ws + DEC_BYTES + BND_BYTES);
        init_kernel<<<1, 256, 0, stream>>>(out, cnt);
        dtw_dp<<<BATCH * GB, LANES, 0, stream>>>(preds, targs, dec, bnd, cnt);
        dtw_bt<<<BATCH, BT_T, 0, stream>>>(preds, targs, subcoef, dec, out);
    } else {
        unsigned* dec = (unsigned*)d_ws;   // 8 MB
        int* cnt = (int*)d_ws;             // unused, init zeroes out[0] only
        init_kernel<<<1, 1, 0, stream>>>(out, cnt);
        dtw_fallback<<<BATCH, 256, 0, stream>>>(preds, targs, subcoef, dec, out);
    }
}

// Round 5
// 737.142 us; speedup vs baseline: 1.5019x; 1.5019x over previous
//
#include <hip/hip_runtime.h>
#include <math.h>

#define BATCH 32
#define NN 1024
#define MM 1024
#define GB 4                    // pipeline stages (blocks) per batch
#define RR 4                    // rows per lane
#define CC 4                    // cols per superstep
#define LANES 64
#define BANDROWS (LANES * RR)   // 256
#define TPB (MM / 4)            // 256 tile-columns
#define NSUP (MM / CC + LANES - 1)  // 319 supersteps
#define GATESS 8                // supersteps per 32-col chunk
#define DEC_WORDS_PER_BATCH ((NN / 4) * (MM / 4))     // 65536
#define DEC_BYTES ((size_t)BATCH * DEC_WORDS_PER_BATCH * 4)   // 8 MB
#define BND_BYTES ((size_t)BATCH * GB * MM * 4)               // 512 KB
#define CNT_INTS (BATCH * GB)
#define REQ_WS (DEC_BYTES + BND_BYTES + (size_t)CNT_INTS * 4)
#define LPATH (NN + MM - 1)     // 2047
#define BT_T 256

__global__ void init_kernel(float* out, int* cnt) {
    const int k = threadIdx.x;
    if (k == 0) out[0] = 0.0f;
    if (k < CNT_INTS) cnt[k] = 0;
}

// ------------- DP: 128 blocks (batch x 4 bands) x 64 lanes -------------------
// Lane t owns rows i0=256g+4t..i0+3. Superstep u: lane t processes the 4x4
// cell tile at rows i0..i0+3, cols j0=4(u-t)..j0+3 (fully valid or skipped).
// Boundary row from lane t-1 via 4 __shfl_up issued at end of prev superstep
// (latency hidden under the 16 independent sqrt ops). Cross-block boundary via
// global float4 + release/acquire chunk counter (every 32 cols). One u32
// decision word per superstep in the 4x4-tile layout: bit ((i&3)*4+(j&3))*2,
// word index [b][i>>2][j>>2] (contiguous per band for bt staging).
__global__ __launch_bounds__(LANES) void dtw_dp(
    const float* __restrict__ preds, const float* __restrict__ targs,
    unsigned* __restrict__ dec, float* __restrict__ bnd, int* __restrict__ cnt)
{
    const int blk = blockIdx.x, b = blk >> 2, g = blk & 3, t = threadIdx.x;
    const float INF = __builtin_inff();

    __shared__ float txy[2 * MM];   // interleaved targ coords (8 KB)
    for (int it = 0; it < MM / LANES; ++it) {
        const int idx = it * LANES + t;
        const float4 t4 = ((const float4*)targs)[(size_t)b * MM + idx];
        txy[2 * idx] = t4.x; txy[2 * idx + 1] = t4.y;
    }
    __syncthreads();

    const int i0 = g * BANDROWS + RR * t;
    float px[RR], py[RR];
    #pragma unroll
    for (int r = 0; r < RR; ++r) {
        const float4 p4 = ((const float4*)preds)[(size_t)b * NN + i0 + r];
        px[r] = p4.x; py[r] = p4.y;
    }
    const int ti = i0 >> 2;                      // 64g + t
    unsigned* __restrict__ decT =
        dec + (size_t)b * DEC_WORDS_PER_BATCH + (size_t)ti * TPB;
    const float4* __restrict__ bndIn4 =
        (const float4*)(bnd + ((size_t)b * GB + (g - 1)) * MM);
    float4* __restrict__ bndOut4 = (float4*)(bnd + ((size_t)b * GB + g) * MM);
    const int* cntIn = cnt + b * GB + (g - 1);
    int* cntOut      = cnt + b * GB + g;

    float Dp[RR], Dbot[CC], bv[CC];
    #pragma unroll
    for (int r = 0; r < RR; ++r) Dp[r] = INF;
    #pragma unroll
    for (int c = 0; c < CC; ++c) { Dbot[c] = INF; bv[c] = INF; }
    // dg for (row i0, col j0): retained bv[3] of prev superstep. Seed: feeding
    // dg=0 at global (0,0) reproduces the reference inf->0 sub (argmin=0 too).
    float bndRet = (g == 0 && t == 0) ? 0.0f : INF;
    int avail = 0;

    float4 ca = ((const float4*)txy)[0], cb = ((const float4*)txy)[1];
    float4 gcur = make_float4(INF, INF, INF, INF), gnxt = gcur;
    if (g > 0) {
        do { __builtin_amdgcn_s_sleep(4);
             avail = __hip_atomic_load(cntIn, __ATOMIC_ACQUIRE,
                                       __HIP_MEMORY_SCOPE_AGENT);
        } while (avail < 1);
        gcur = bndIn4[0];
    }

    for (int u = 0; u < NSUP; ++u) {
        if (g > 0 && u > 0 && u < TPB) {
            if ((u & (GATESS - 1)) == 0) {
                const int need = (u >> 3) + 1;
                if (avail < need) {
                    do { __builtin_amdgcn_s_sleep(4);
                         avail = __hip_atomic_load(cntIn, __ATOMIC_ACQUIRE,
                                                   __HIP_MEMORY_SCOPE_AGENT);
                    } while (avail < need);
                }
                gcur = bndIn4[u];
            } else {
                gcur = gnxt;
            }
        }
        if (t == 0) {   // lane 0's boundary row comes from the previous band
            const bool gb = (g > 0 && u < TPB);
            bv[0] = gb ? gcur.x : INF; bv[1] = gb ? gcur.y : INF;
            bv[2] = gb ? gcur.z : INF; bv[3] = gb ? gcur.w : INF;
        }
        const int j0 = CC * (u - t);
        const bool act = (u >= t) && (u < t + TPB);
        if (act) {
            const float cx[CC] = {ca.x, ca.z, cb.x, cb.z};
            const float cy[CC] = {ca.y, ca.w, cb.y, cb.w};
            float cost[RR][CC];
            #pragma unroll
            for (int c = 0; c < CC; ++c)
                #pragma unroll
                for (int r = 0; r < RR; ++r) {
                    const float dx = px[r] - cx[c], dy = py[r] - cy[c];
                    cost[r][c] = __builtin_amdgcn_sqrtf(dx * dx + dy * dy);
                }
            unsigned word = 0;
            #pragma unroll
            for (int c = 0; c < CC; ++c) {
                float up = bv[c];                       // D[i0-1][j0+c]
                float dg = (c == 0) ? bndRet : bv[c - 1];
                #pragma unroll
                for (int r = 0; r < RR; ++r) {
                    const float lf = Dp[r];             // D[i0+r][j0+c-1]
                    // JAX argmin over [dg, up, lf], first-minimum tie order.
                    const unsigned m = (dg <= up && dg <= lf) ? 0u
                                     : ((up <= lf) ? 1u : 2u);
                    const float D = cost[r][c] + fminf(dg, fminf(up, lf));
                    word |= m << ((r * 4 + c) * 2);
                    dg = lf; up = D; Dp[r] = D;
                }
                Dbot[c] = up;
            }
            decT[j0 >> 2] = word;
            if (g < GB - 1 && t == LANES - 1) {
                bndOut4[j0 >> 2] = make_float4(Dbot[0], Dbot[1], Dbot[2], Dbot[3]);
                if (((j0 >> 2) & (GATESS - 1)) == GATESS - 1)
                    __hip_atomic_store(cntOut, (j0 >> 5) + 1, __ATOMIC_RELEASE,
                                       __HIP_MEMORY_SCOPE_AGENT);
            }
        }
        // Prep next superstep (uniform): retain dg, exchange boundary, prefetch.
        bndRet = bv[CC - 1];
        #pragma unroll
        for (int c = 0; c < CC; ++c) bv[c] = __shfl_up(Dbot[c], 1);
        const int un = u + 1;
        if (un >= t && un < t + TPB) {
            const int jn = CC * (un - t);
            ca = ((const float4*)txy)[jn >> 1];
            cb = ((const float4*)txy)[(jn >> 1) + 1];
        }
        if (g > 0 && un < TPB && (un & (GATESS - 1)) != 0) gnxt = bndIn4[un];
    }
}

// ------------- Backtrack: 32 blocks x 256 threads ----------------------------
__device__ inline void bt_walk4(const unsigned* __restrict__ sdec, int roff,
                                int iLow, int& i, int& j, int& n,
                                unsigned* __restrict__ path)
{
    int ri = i >> 2, jc = j >> 2;
    unsigned w = sdec[(ri - roff) * 256 + jc];
    while (true) {
        const int base = (ri - roff) * 256 + jc;
        const unsigned wl = sdec[(jc > 0)    ? base - 1   : base];
        const unsigned wu = sdec[(ri > roff) ? base - 256 : base];
        const unsigned wd = sdec[(ri > roff && jc > 0) ? base - 257 : base];
        bool done = false, susp = false;
        while (true) {
            path[n++] = ((unsigned)i << 16) | (unsigned)j;
            if ((i | j) == 0) { done = true; break; }
            const unsigned m = (w >> (((i & 3) * 4 + (j & 3)) * 2)) & 3u;
            i -= (m != 2u); j -= (m != 1u);
            if (i < iLow) { susp = true; break; }
            if ((i >> 2) != ri || (j >> 2) != jc) break;
        }
        if (done || susp) break;
        const int nri = i >> 2, njc = j >> 2;
        w = (nri == ri) ? wl : ((njc == jc) ? wu : wd);
        ri = nri; jc = njc;
    }
}

__global__ __launch_bounds__(BT_T) void dtw_bt(
    const float* __restrict__ preds, const float* __restrict__ targs,
    const float* __restrict__ subcoef, const unsigned* __restrict__ dec,
    float* __restrict__ out)
{
    const int b = blockIdx.x, t = threadIdx.x;
    __shared__ float pxA[NN], pyA[NN], txA[MM], tyA[MM];
    __shared__ unsigned sdec[128 * 256];     // 128 KB (half the batch's words)
    __shared__ unsigned path[LPATH + 1];
    __shared__ int sI, sJ, sN;
    __shared__ float wsum[BT_T / 64];

    for (int it = 0; it < NN / BT_T; ++it) {
        const int idx = it * BT_T + t;
        const float4 p4 = ((const float4*)preds)[(size_t)b * NN + idx];
        pxA[idx] = p4.x; pyA[idx] = p4.y;
        const float4 t4 = ((const float4*)targs)[(size_t)b * MM + idx];
        txA[idx] = t4.x; tyA[idx] = t4.y;
    }
    const unsigned* __restrict__ decB = dec + (size_t)b * DEC_WORDS_PER_BATCH;

    // Phase A: tile-rows 128..255 (rows 512..1023) — contiguous copy.
    {
        uint4* s4 = (uint4*)sdec;
        const uint4* g4 = (const uint4*)(decB + 128 * 256);
        for (int k = t; k < 8192; k += BT_T) s4[k] = g4[k];
    }
    __syncthreads();
    if (t == 0) {
        int i = NN - 1, j = MM - 1, n = 0;
        bt_walk4(sdec, 128, 512, i, j, n, path);
        sI = i; sJ = j; sN = n;
    }
    __syncthreads();
    // Phase B: tile-rows 0..127.
    {
        uint4* s4 = (uint4*)sdec;
        const uint4* g4 = (const uint4*)decB;
        for (int k = t; k < 8192; k += BT_T) s4[k] = g4[k];
    }
    __syncthreads();
    if (t == 0) {
        int i = sI, j = sJ, n = sN;
        bt_walk4(sdec, 0, 0, i, j, n, path);
        sN = n;
    }
    __syncthreads();

    const float sc0 = subcoef[0], sc1 = subcoef[1];
    const int n = sN;
    float acc = 0.0f;
    for (int p = t; p < n; p += BT_T) {
        const unsigned e = path[p];
        const int i = (int)(e >> 16), j = (int)(e & 0xffffu);
        acc += fabsf(pxA[i] - txA[j]) * sc0 + fabsf(pyA[i] - tyA[j]) * sc1;
    }
    #pragma unroll
    for (int o = 32; o > 0; o >>= 1) acc += __shfl_down(acc, o);
    if ((t & 63) == 0) wsum[t >> 6] = acc;
    __syncthreads();
    if (t == 0) atomicAdd(out, (wsum[0] + wsum[1]) + (wsum[2] + wsum[3]));
}

// ------------- Fallback (R1 kernel, only if ws too small) --------------------
__global__ __launch_bounds__(256) void dtw_fallback(
    const float* __restrict__ preds, const float* __restrict__ targs,
    const float* __restrict__ subcoef, unsigned* __restrict__ dec,
    float* __restrict__ out)
{
    const int b = blockIdx.x;
    const int t = threadIdx.x;
    const float INF = __builtin_inff();
    __shared__ float px[NN], py[NN];
    __shared__ float txy[2 * MM];
    __shared__ float bbuf[2][256];

    for (int it = 0; it < NN / 256; ++it) {
        const int idx = it * 256 + t;
        const float4 p4 = ((const float4*)preds)[(size_t)b * NN + idx];
        px[idx] = p4.x; py[idx] = p4.y;
        const float4 t4 = ((const float4*)targs)[(size_t)b * MM + idx];
        txy[2 * idx] = t4.x; txy[2 * idx + 1] = t4.y;
    }
    bbuf[0][t] = INF; bbuf[1][t] = INF;
    __syncthreads();

    float pxr[4], pyr[4], Dp[4];
    #pragma unroll
    for (int r = 0; r < 4; ++r) {
        pxr[r] = px[4 * t + r]; pyr[r] = py[4 * t + r]; Dp[r] = INF;
    }
    float dgB = (t == 0) ? 0.0f : INF;
    unsigned packed = 0;
    unsigned* decB = dec + (size_t)b * 65536;
    for (int s = 0; s < MM + 255; ++s) {
        const int j = s - t;
        const float upB = (t == 0) ? INF : bbuf[(s + 1) & 1][t - 1];
        if (j >= 0 && j < MM) {
            const float txj = txy[2 * j], tyj = txy[2 * j + 1];
            float up = upB, dg = dgB;
            unsigned mbits = 0;
            #pragma unroll
            for (int r = 0; r < 4; ++r) {
                const float dx = pxr[r] - txj, dy = pyr[r] - tyj;
                const float c = sqrtf(dx * dx + dy * dy);
                const float lf = Dp[r];
                const unsigned m = (dg <= up && dg <= lf) ? 0u
                                 : ((up <= lf) ? 1u : 2u);
                mbits |= m << (r * 8 + (j & 3) * 2);
                const float Dc = c + fminf(up, fminf(dg, lf));
                dg = lf; up = Dc; Dp[r] = Dc;
            }
            packed |= mbits;
            if ((j & 3) == 3) { decB[(unsigned)t * 256 + (j >> 2)] = packed; packed = 0; }
            bbuf[s & 1][t] = Dp[3];
        }
        dgB = upB;
        __syncthreads();
    }
    __threadfence_block();
    __syncthreads();
    if (t == 0) {
        const float sc0 = subcoef[0], sc1 = subcoef[1];
        int i = NN - 1, jj = MM - 1;
        float loss = 0.0f;
        int ti = i >> 2, tj = jj >> 2;
        unsigned w = decB[ti * 256 + tj];
        while (true) {
            const int tjl = (tj > 0) ? tj - 1 : 0;
            const int til = (ti > 0) ? ti - 1 : 0;
            const unsigned wl = decB[ti * 256 + tjl];
            const unsigned wu = decB[til * 256 + tj];
            const unsigned wd = decB[til * 256 + tjl];
            bool done = false;
            while (true) {
                loss += fabsf(px[i] - txy[2 * jj]) * sc0
                      + fabsf(py[i] - txy[2 * jj + 1]) * sc1;
                if ((i | jj) == 0) { done = true; break; }
                const unsigned m = (w >> (((i & 3) * 4 + (jj & 3)) * 2)) & 3u;
                i -= (m != 2u); jj -= (m != 1u);
                if ((i >> 2) != ti || (jj >> 2) != tj) break;
            }
            if (done) break;
            const int nti = i >> 2, ntj = jj >> 2;
            w = (nti == ti) ? wl : ((ntj == tj) ? wu : wd);
            ti = nti; tj = ntj;
        }
        atomicAdd(out, loss);
    }
}

extern "C" void kernel_launch(void* const* d_in, const int* in_sizes, int n_in,
                              void* d_out, int out_size, void* d_ws, size_t ws_size,
                              hipStream_t stream) {
    const float* preds   = (const float*)d_in[0];
    const float* targs   = (const float*)d_in[1];
    const float* subcoef = (const float*)d_in[2];
    float* out = (float*)d_out;

    if (ws_size >= REQ_WS) {
        unsigned* dec = (unsigned*)d_ws;
        float* bnd = (float*)((char*)d_ws + DEC_BYTES);
        int* cnt = (int*)((char*)d_ws + DEC_BYTES + BND_BYTES);
        init_kernel<<<1, 256, 0, stream>>>(out, cnt);
        dtw_dp<<<BATCH * GB, LANES, 0, stream>>>(preds, targs, dec, bnd, cnt);
        dtw_bt<<<BATCH, BT_T, 0, stream>>>(preds, targs, subcoef, dec, out);
    } else {
        unsigned* dec = (unsigned*)d_ws;
        int* cnt = (int*)d_ws;
        init_kernel<<<1, 1, 0, stream>>>(out, cnt);
        dtw_fallback<<<BATCH, 256, 0, stream>>>(preds, targs, subcoef, dec, out);
    }
}

// Round 6
// 598.160 us; speedup vs baseline: 1.8508x; 1.2323x over previous
//
#include <hip/hip_runtime.h>
#include <math.h>

#define BATCH 32
#define NN 1024
#define MM 1024
#define RR 4                    // rows per lane
#define CC 4                    // cols per superstep
#define LANES 64
#define NWAVE 4
#define TPB (MM / 4)            // tile-columns = lane-local supersteps (256)
#define NSUP (TPB + LANES - 1)  // 319 supersteps per wave
#define LAG 72                  // wave-to-wave lag (63 lane skew + 9 margin)
#define TOT (NSUP + (NWAVE - 1) * LAG)   // 535 iterations
#define DEPTH 32                // LDS boundary ring depth (float4 entries)
#define DEC_WORDS_PER_BATCH ((NN / 4) * (MM / 4))     // 65536
#define DEC_BYTES ((size_t)BATCH * DEC_WORDS_PER_BATCH * 4)   // 8 MB
#define REQ_WS DEC_BYTES
#define LPATH (NN + MM - 1)     // 2047

__global__ void init_kernel(float* out) { out[0] = 0.0f; }

// ---- Backtrack word-walk (4x4 tile words, 3-candidate prefetch) -------------
__device__ inline void bt_walk4(const unsigned* __restrict__ sdec, int roff,
                                int iLow, int& i, int& j, int& n,
                                unsigned* __restrict__ path)
{
    int ri = i >> 2, jc = j >> 2;
    unsigned w = sdec[(ri - roff) * 256 + jc];
    while (true) {
        const int base = (ri - roff) * 256 + jc;
        const unsigned wl = sdec[(jc > 0)    ? base - 1   : base];
        const unsigned wu = sdec[(ri > roff) ? base - 256 : base];
        const unsigned wd = sdec[(ri > roff && jc > 0) ? base - 257 : base];
        bool done = false, susp = false;
        while (true) {
            path[n++] = ((unsigned)i << 16) | (unsigned)j;
            if ((i | j) == 0) { done = true; break; }
            const unsigned m = (w >> (((i & 3) * 4 + (j & 3)) * 2)) & 3u;
            i -= (m != 2u); j -= (m != 1u);
            if (i < iLow) { susp = true; break; }
            if ((i >> 2) != ri || (j >> 2) != jc) break;
        }
        if (done || susp) break;
        const int nri = i >> 2, njc = j >> 2;
        w = (nri == ri) ? wl : ((njc == jc) ? wu : wd);
        ri = nri; jc = njc;
    }
}

// ---- Fused DP + backtrack: 32 blocks (one per batch) x 256 threads ----------
// Wave w owns rows [256w, 256w+256); lane l owns rows i0=256w+4l..i0+3.
// Lane l's local superstep ul covers cols j0=4(ul-l)..j0+3. Wave w runs at
// global iteration u = ul + LAG*w. Intra-wave boundary: 4 __shfl_up per
// superstep. Cross-wave boundary: 32-deep LDS float4 ring; entry written at
// iter X is read at iter X+9, and a __syncthreads every 8 iters guarantees
// exactly >=1 barrier between write and read (LDS-visibility safe, no
// atomics, no global traffic). Decisions: one u32 per 4x4 tile, bit
// ((i&3)*4+(j&3))*2, layout dec[b][i>>2][j>>2].
__global__ __launch_bounds__(256, 1) void dtw_fused(
    const float* __restrict__ preds, const float* __restrict__ targs,
    const float* __restrict__ subcoef, unsigned* __restrict__ dec,
    float* __restrict__ out)
{
    const int b = blockIdx.x, t = threadIdx.x;
    const int l = t & 63, w = t >> 6;
    const float INF = __builtin_inff();

    __shared__ float pxA[NN], pyA[NN], txA[MM], tyA[MM];   // 16 KB
    __shared__ float4 ring[NWAVE - 1][DEPTH];              // 1.5 KB
    __shared__ unsigned sdec[128 * 256];                   // 128 KB
    __shared__ unsigned path[LPATH + 1];                   // 8 KB
    __shared__ int sI, sJ, sN;
    __shared__ float wsum[NWAVE];

    for (int it = 0; it < NN / 256; ++it) {
        const int idx = it * 256 + t;
        const float4 p4 = ((const float4*)preds)[(size_t)b * NN + idx];
        pxA[idx] = p4.x; pyA[idx] = p4.y;
        const float4 t4 = ((const float4*)targs)[(size_t)b * MM + idx];
        txA[idx] = t4.x; tyA[idx] = t4.y;
    }
    __syncthreads();

    // ---------------- DP ----------------
    const int i0 = (w << 8) + (l << 2);
    const float4 px4 = ((const float4*)pxA)[i0 >> 2];
    const float4 py4 = ((const float4*)pyA)[i0 >> 2];
    const float px[RR] = {px4.x, px4.y, px4.z, px4.w};
    const float py[RR] = {py4.x, py4.y, py4.z, py4.w};
    unsigned* __restrict__ decT =
        dec + (size_t)b * DEC_WORDS_PER_BATCH + (size_t)(i0 >> 2) * TPB;

    float Dp[RR], Dbot[CC], bv[CC];
    #pragma unroll
    for (int r = 0; r < RR; ++r) Dp[r] = INF;
    #pragma unroll
    for (int c = 0; c < CC; ++c) { Dbot[c] = INF; bv[c] = INF; }
    // dg for (i0, j0) = previous superstep's bv[3]. Seed: dg=0 at global (0,0)
    // reproduces the reference's inf->0 substitution exactly (argmin=0 too).
    float bndRet = (w == 0 && l == 0) ? 0.0f : INF;
    float4 gcur = make_float4(INF, INF, INF, INF);
    float4 tx4 = ((const float4*)txA)[0], ty4 = ((const float4*)tyA)[0];

    for (int u = 0; u < TOT; ++u) {
        const int ul = u - LAG * w;      // this wave's local superstep
        if (l == 0) {                    // boundary row from previous band
            const bool gb = (w > 0) && (ul >= 0) && (ul < TPB);
            bv[0] = gb ? gcur.x : INF; bv[1] = gb ? gcur.y : INF;
            bv[2] = gb ? gcur.z : INF; bv[3] = gb ? gcur.w : INF;
        }
        const bool act = (ul >= l) && (ul < l + TPB);
        if (act) {
            const int j0 = CC * (ul - l);
            const float cx[CC] = {tx4.x, tx4.y, tx4.z, tx4.w};
            const float cy[CC] = {ty4.x, ty4.y, ty4.z, ty4.w};
            float cost[RR][CC];
            #pragma unroll
            for (int c = 0; c < CC; ++c)
                #pragma unroll
                for (int r = 0; r < RR; ++r) {
                    const float dx = px[r] - cx[c], dy = py[r] - cy[c];
                    cost[r][c] = __builtin_amdgcn_sqrtf(dx * dx + dy * dy);
                }
            unsigned word = 0;
            #pragma unroll
            for (int c = 0; c < CC; ++c) {
                float up = bv[c];                       // D[i0-1][j0+c]
                float dg = (c == 0) ? bndRet : bv[c - 1];
                #pragma unroll
                for (int r = 0; r < RR; ++r) {
                    const float lf = Dp[r];             // D[i0+r][j0+c-1]
                    // JAX argmin over [dg, up, lf], first-minimum tie order.
                    const unsigned m = (dg <= up && dg <= lf) ? 0u
                                     : ((up <= lf) ? 1u : 2u);
                    const float D = cost[r][c] + fminf(dg, fminf(up, lf));
                    word |= m << ((r * 4 + c) * 2);
                    dg = lf; up = D; Dp[r] = D;
                }
                Dbot[c] = up;
            }
            decT[j0 >> 2] = word;
            if (l == LANES - 1 && w < NWAVE - 1)        // publish bottom row
                ring[w][ul & (DEPTH - 1)] =
                    make_float4(Dbot[0], Dbot[1], Dbot[2], Dbot[3]);
        }
        // Uniform epilogue: retain dg, exchange boundary, prefetch next.
        bndRet = bv[CC - 1];
        #pragma unroll
        for (int c = 0; c < CC; ++c) bv[c] = __shfl_up(Dbot[c], 1);
        const int un = ul + 1;
        if (un >= l && un < l + TPB) {
            const int jn = CC * (un - l);
            tx4 = ((const float4*)txA)[jn >> 2];
            ty4 = ((const float4*)tyA)[jn >> 2];
        }
        if (l == 0 && w > 0 && un >= 0 && un < TPB)
            gcur = ring[w - 1][(un + 63) & (DEPTH - 1)];
        if ((u & 7) == 7) __syncthreads();
    }

    __threadfence_block();   // drain dec stores (vmcnt) before re-reading
    __syncthreads();

    // ---------------- Backtrack ----------------
    const unsigned* __restrict__ decB = dec + (size_t)b * DEC_WORDS_PER_BATCH;
    // Phase A: tile-rows 128..255 (rows 512..1023) — contiguous 128 KB copy.
    {
        uint4* s4 = (uint4*)sdec;
        const uint4* g4 = (const uint4*)(decB + 128 * 256);
        for (int k = t; k < 8192; k += 256) s4[k] = g4[k];
    }
    __syncthreads();
    if (t == 0) {
        int i = NN - 1, j = MM - 1, n = 0;
        bt_walk4(sdec, 128, 512, i, j, n, path);
        sI = i; sJ = j; sN = n;
    }
    __syncthreads();
    // Phase B: tile-rows 0..127.
    {
        uint4* s4 = (uint4*)sdec;
        const uint4* g4 = (const uint4*)decB;
        for (int k = t; k < 8192; k += 256) s4[k] = g4[k];
    }
    __syncthreads();
    if (t == 0) {
        int i = sI, j = sJ, n = sN;
        bt_walk4(sdec, 0, 0, i, j, n, path);
        sN = n;
    }
    __syncthreads();

    // ---------------- Parallel loss over the path ----------------
    const float sc0 = subcoef[0], sc1 = subcoef[1];
    const int n = sN;
    float acc = 0.0f;
    for (int p = t; p < n; p += 256) {
        const unsigned e = path[p];
        const int i = (int)(e >> 16), j = (int)(e & 0xffffu);
        acc += fabsf(pxA[i] - txA[j]) * sc0 + fabsf(pyA[i] - tyA[j]) * sc1;
    }
    #pragma unroll
    for (int o = 32; o > 0; o >>= 1) acc += __shfl_down(acc, o);
    if ((t & 63) == 0) wsum[t >> 6] = acc;
    __syncthreads();
    if (t == 0) atomicAdd(out, (wsum[0] + wsum[1]) + (wsum[2] + wsum[3]));
}

// ------------- Fallback (R1 kernel, only if ws too small) --------------------
__global__ __launch_bounds__(256) void dtw_fallback(
    const float* __restrict__ preds, const float* __restrict__ targs,
    const float* __restrict__ subcoef, unsigned* __restrict__ dec,
    float* __restrict__ out)
{
    const int b = blockIdx.x;
    const int t = threadIdx.x;
    const float INF = __builtin_inff();
    __shared__ float px[NN], py[NN];
    __shared__ float txy[2 * MM];
    __shared__ float bbuf[2][256];

    for (int it = 0; it < NN / 256; ++it) {
        const int idx = it * 256 + t;
        const float4 p4 = ((const float4*)preds)[(size_t)b * NN + idx];
        px[idx] = p4.x; py[idx] = p4.y;
        const float4 t4 = ((const float4*)targs)[(size_t)b * MM + idx];
        txy[2 * idx] = t4.x; txy[2 * idx + 1] = t4.y;
    }
    bbuf[0][t] = INF; bbuf[1][t] = INF;
    __syncthreads();

    float pxr[4], pyr[4], Dp[4];
    #pragma unroll
    for (int r = 0; r < 4; ++r) {
        pxr[r] = px[4 * t + r]; pyr[r] = py[4 * t + r]; Dp[r] = INF;
    }
    float dgB = (t == 0) ? 0.0f : INF;
    unsigned packed = 0;
    unsigned* decB = dec + (size_t)b * 65536;
    for (int s = 0; s < MM + 255; ++s) {
        const int j = s - t;
        const float upB = (t == 0) ? INF : bbuf[(s + 1) & 1][t - 1];
        if (j >= 0 && j < MM) {
            const float txj = txy[2 * j], tyj = txy[2 * j + 1];
            float up = upB, dg = dgB;
            unsigned mbits = 0;
            #pragma unroll
            for (int r = 0; r < 4; ++r) {
                const float dx = pxr[r] - txj, dy = pyr[r] - tyj;
                const float c = sqrtf(dx * dx + dy * dy);
                const float lf = Dp[r];
                const unsigned m = (dg <= up && dg <= lf) ? 0u
                                 : ((up <= lf) ? 1u : 2u);
                mbits |= m << (r * 8 + (j & 3) * 2);
                const float Dc = c + fminf(up, fminf(dg, lf));
                dg = lf; up = Dc; Dp[r] = Dc;
            }
            packed |= mbits;
            if ((j & 3) == 3) { decB[(unsigned)t * 256 + (j >> 2)] = packed; packed = 0; }
            bbuf[s & 1][t] = Dp[3];
        }
        dgB = upB;
        __syncthreads();
    }
    __threadfence_block();
    __syncthreads();
    if (t == 0) {
        const float sc0 = subcoef[0], sc1 = subcoef[1];
        int i = NN - 1, jj = MM - 1;
        float loss = 0.0f;
        int ti = i >> 2, tj = jj >> 2;
        unsigned wv = decB[ti * 256 + tj];
        while (true) {
            const int tjl = (tj > 0) ? tj - 1 : 0;
            const int til = (ti > 0) ? ti - 1 : 0;
            const unsigned wl = decB[ti * 256 + tjl];
            const unsigned wu = decB[til * 256 + tj];
            const unsigned wd = decB[til * 256 + tjl];
            bool done = false;
            while (true) {
                loss += fabsf(px[i] - txy[2 * jj]) * sc0
                      + fabsf(py[i] - txy[2 * jj + 1]) * sc1;
                if ((i | jj) == 0) { done = true; break; }
                const unsigned m = (wv >> (((i & 3) * 4 + (jj & 3)) * 2)) & 3u;
                i -= (m != 2u); jj -= (m != 1u);
                if ((i >> 2) != ti || (jj >> 2) != tj) break;
            }
            if (done) break;
            const int nti = i >> 2, ntj = jj >> 2;
            wv = (nti == ti) ? wl : ((ntj == tj) ? wu : wd);
            ti = nti; tj = ntj;
        }
        atomicAdd(out, loss);
    }
}

extern "C" void kernel_launch(void* const* d_in, const int* in_sizes, int n_in,
                              void* d_out, int out_size, void* d_ws, size_t ws_size,
                              hipStream_t stream) {
    const float* preds   = (const float*)d_in[0];
    const float* targs   = (const float*)d_in[1];
    const float* subcoef = (const float*)d_in[2];
    float* out = (float*)d_out;
    unsigned* dec = (unsigned*)d_ws;   // 8 MB

    init_kernel<<<1, 1, 0, stream>>>(out);
    if (ws_size >= REQ_WS) {
        dtw_fused<<<BATCH, 256, 0, stream>>>(preds, targs, subcoef, dec, out);
    } else {
        dtw_fallback<<<BATCH, 256, 0, stream>>>(preds, targs, subcoef, dec, out);
    }
}